// Round 1
// baseline (1654.171 us; speedup 1.0000x reference)
//
#include <hip/hip_runtime.h>
#include <hip/hip_bf16.h>
#include <stdint.h>

typedef __hip_bfloat16 bf16;
typedef __attribute__((ext_vector_type(8))) short short8;   // bf16x8 MFMA A/B frag
typedef __attribute__((ext_vector_type(4))) float f32x4;    // MFMA C/D frag

#define MFMA16(a, b, c) __builtin_amdgcn_mfma_f32_16x16x32_bf16((a), (b), (c), 0, 0, 0)

__device__ inline short8 frag16(const void* p) {
    union { uint4 u; short8 s; } cv;
    cv.u = *(const uint4*)p;
    return cv.s;
}

// async global->LDS, 16B per lane; LDS dest = wave-uniform base + lane*16
__device__ inline void gld_lds16(const void* g, void* l) {
    __builtin_amdgcn_global_load_lds(
        (__attribute__((address_space(1))) void*)(g),
        (__attribute__((address_space(3))) void*)(l), 16, 0, 0);
}

// ---------------- fp32 -> bf16 converts ----------------
__global__ __launch_bounds__(256) void cvt_inputs(
    const float* __restrict__ a, const float* __restrict__ b, const float* __restrict__ c,
    bf16* __restrict__ oa, bf16* __restrict__ ob, bf16* __restrict__ oc) {
    const float* in = blockIdx.z == 0 ? a : (blockIdx.z == 1 ? b : c);
    bf16* out = blockIdx.z == 0 ? oa : (blockIdx.z == 1 ? ob : oc);
    size_t i = ((size_t)blockIdx.x * 256 + threadIdx.x) * 4;
    float4 v = *(const float4*)(in + i);
    union { bf16 h[4]; uint2 u; } o;
    o.h[0] = __float2bfloat16(v.x); o.h[1] = __float2bfloat16(v.y);
    o.h[2] = __float2bfloat16(v.z); o.h[3] = __float2bfloat16(v.w);
    *(uint2*)(out + i) = o.u;
}

__global__ __launch_bounds__(256) void cvt_weights(
    const float* __restrict__ a, const float* __restrict__ b,
    const float* __restrict__ c, const float* __restrict__ d,
    bf16* __restrict__ oa, bf16* __restrict__ ob, bf16* __restrict__ oc, bf16* __restrict__ od) {
    const float* in = blockIdx.z == 0 ? a : (blockIdx.z == 1 ? b : (blockIdx.z == 2 ? c : d));
    bf16* out = blockIdx.z == 0 ? oa : (blockIdx.z == 1 ? ob : (blockIdx.z == 2 ? oc : od));
    size_t i = ((size_t)blockIdx.x * 256 + threadIdx.x) * 4;
    float4 v = *(const float4*)(in + i);
    union { bf16 h[4]; uint2 u; } o;
    o.h[0] = __float2bfloat16(v.x); o.h[1] = __float2bfloat16(v.y);
    o.h[2] = __float2bfloat16(v.z); o.h[3] = __float2bfloat16(v.w);
    *(uint2*)(out + i) = o.u;
}

// ---------------- GEMM mainloop: C[128x128] = X[128xK] * W[128xK]^T, K=1024 ----------------
// BK=64, 4 waves in 2x2, each wave 64x64 (4x4 tiles of 16x16x32 MFMA).
// LDS layout: [row][64] packed, 16B chunks XOR-swizzled by (row&7) so frag reads are ~conflict-free
// while staying compatible with global_load_lds' linear lane*16 destination.
__device__ inline void gemm_mainloop(const bf16* __restrict__ X, const bf16* __restrict__ W,
                                     int m0, int n0, bf16* As, bf16* Bs, f32x4 acc[4][4]) {
    const int tid = threadIdx.x;
    const int wave = tid >> 6, lane = tid & 63;
    const int wm = wave >> 1, wn = wave & 1;
    const int row8 = wave * 8 + (lane >> 3);
    const int cph = lane & 7;
    for (int kt = 0; kt < 16; ++kt) {
        __syncthreads();
        for (int r = 0; r < 4; ++r) {
            int row = r * 32 + row8;
            int cg = cph ^ (row & 7);   // which logical 16B chunk lands in slot (lane&7)
            gld_lds16(X + (size_t)(m0 + row) * 1024 + kt * 64 + cg * 8, As + (r * 32 + wave * 8) * 64);
            gld_lds16(W + (size_t)(n0 + row) * 1024 + kt * 64 + cg * 8, Bs + (r * 32 + wave * 8) * 64);
        }
        __syncthreads();
        for (int kk = 0; kk < 2; ++kk) {
            short8 af[4], bfr[4];
            for (int i = 0; i < 4; ++i) {
                int rowA = wm * 64 + i * 16 + (lane & 15);
                int ca = (kk * 4 + (lane >> 4)) ^ (rowA & 7);
                af[i] = frag16(As + rowA * 64 + ca * 8);
                int rowB = wn * 64 + i * 16 + (lane & 15);
                int cb = (kk * 4 + (lane >> 4)) ^ (rowB & 7);
                bfr[i] = frag16(Bs + rowB * 64 + cb * 8);
            }
            for (int i = 0; i < 4; ++i)
                for (int j = 0; j < 4; ++j)
                    acc[i][j] = MFMA16(af[i], bfr[j], acc[i][j]);
        }
    }
}

// z selects Q/K/V. Output layout [b, h, s, dh] bf16 (ready as MFMA frags for attention).
__global__ __launch_bounds__(256) void proj_gemm(
    const bf16* __restrict__ Xq, const bf16* __restrict__ Xk, const bf16* __restrict__ Xv,
    const bf16* __restrict__ Wq, const bf16* __restrict__ Wk, const bf16* __restrict__ Wv,
    bf16* __restrict__ Q, bf16* __restrict__ K, bf16* __restrict__ V) {
    __shared__ __align__(16) bf16 As[128 * 64];
    __shared__ __align__(16) bf16 Bs[128 * 64];
    const int z = blockIdx.z;
    const bf16* X = z == 0 ? Xq : (z == 1 ? Xk : Xv);
    const bf16* W = z == 0 ? Wq : (z == 1 ? Wk : Wv);
    bf16* O = z == 0 ? Q : (z == 1 ? K : V);
    const int m0 = blockIdx.x * 128, n0 = blockIdx.y * 128;
    f32x4 acc[4][4] = {};
    gemm_mainloop(X, W, m0, n0, As, Bs, acc);
    const int lane = threadIdx.x & 63, wave = threadIdx.x >> 6;
    const int wm = wave >> 1, wn = wave & 1;
    for (int i = 0; i < 4; ++i) {
        int gmb = m0 + wm * 64 + i * 16 + (lane >> 4) * 4;
        for (int j = 0; j < 4; ++j) {
            int gn = n0 + wn * 64 + j * 16 + (lane & 15);
            int h = gn >> 6, dh = gn & 63;
            for (int t = 0; t < 4; ++t) {
                int m = gmb + t;
                int b = m >> 11, s = m & 2047;
                O[(((size_t)(b * 16 + h) * 2048 + s) << 6) + dh] = __float2bfloat16(acc[i][j][t]);
            }
        }
    }
}

// fc GEMM: Y = ctx * Wfc^T + resid (fp32 out for LayerNorm)
__global__ __launch_bounds__(256) void fc_gemm(
    const bf16* __restrict__ X, const bf16* __restrict__ W,
    const float* __restrict__ resid, float* __restrict__ Y) {
    __shared__ __align__(16) bf16 As[128 * 64];
    __shared__ __align__(16) bf16 Bs[128 * 64];
    const int m0 = blockIdx.x * 128, n0 = blockIdx.y * 128;
    f32x4 acc[4][4] = {};
    gemm_mainloop(X, W, m0, n0, As, Bs, acc);
    const int lane = threadIdx.x & 63, wave = threadIdx.x >> 6;
    const int wm = wave >> 1, wn = wave & 1;
    for (int i = 0; i < 4; ++i) {
        int gmb = m0 + wm * 64 + i * 16 + (lane >> 4) * 4;
        for (int j = 0; j < 4; ++j) {
            int gn = n0 + wn * 64 + j * 16 + (lane & 15);
            for (int t = 0; t < 4; ++t) {
                size_t idx = (size_t)(gmb + t) * 1024 + gn;
                Y[idx] = acc[i][j][t] + resid[idx];
            }
        }
    }
}

// V [b,h,s,64] -> Vt [b,h,64,s] so PV B-frags are contiguous along s
__global__ __launch_bounds__(256) void transpose_v(const bf16* __restrict__ V, bf16* __restrict__ Vt) {
    __shared__ bf16 tile[64][65];
    const int bh = blockIdx.y;
    const int s0 = blockIdx.x * 64;
    const size_t base = (size_t)bh * 2048 * 64;
    for (int i = 0; i < 16; ++i) {
        int idx = i * 256 + threadIdx.x;
        int r = idx >> 6, cc = idx & 63;
        tile[r][cc] = V[base + (size_t)(s0 + r) * 64 + cc];
    }
    __syncthreads();
    for (int i = 0; i < 16; ++i) {
        int idx = i * 256 + threadIdx.x;
        int d = idx >> 6, ss = idx & 63;
        Vt[base + (size_t)d * 2048 + s0 + ss] = tile[ss][d];
    }
}

// ---------------- fused attention ----------------
// grid (16, 64): block = 4 waves, each wave owns 32 q-rows of one (b,h).
// Pass A: l = sum(exp(s/8)) per row (no max-shift: scores are O(1), fp32-safe).
// Pass B: recompute S, write attn = exp(s/8)/l (fp32, d_out), P->LDS->A-frag, O += P*V.
__global__ __launch_bounds__(256) void attn_kernel(
    const bf16* __restrict__ Q, const bf16* __restrict__ K, const bf16* __restrict__ Vt,
    float* __restrict__ attn, bf16* __restrict__ ctx) {
    __shared__ __align__(16) bf16 Pbuf[4][32 * 40];   // per-wave 32x32 P chunk, stride 40 (pad)
    const int lane = threadIdx.x & 63, wave = threadIdx.x >> 6;
    const int c = lane & 15, qd = lane >> 4;
    const int bh = blockIdx.y;
    const int b = bh >> 4, h = bh & 15;
    const int q0 = blockIdx.x * 128 + wave * 32;
    const bf16* Qp = Q + (size_t)bh * 2048 * 64;
    const bf16* Kp = K + (size_t)bh * 2048 * 64;
    const bf16* Vp = Vt + (size_t)bh * 64 * 2048;
    float* Ap = attn + (size_t)bh * 2048 * 2048;

    short8 qf[2][2];
    for (int mt = 0; mt < 2; ++mt)
        for (int kk = 0; kk < 2; ++kk)
            qf[mt][kk] = frag16(Qp + (size_t)(q0 + mt * 16 + c) * 64 + kk * 32 + qd * 8);

    // ---- pass A: per-lane partial row sums of exp ----
    float lpart[2][4] = {};
    for (int n0 = 0; n0 < 2048; n0 += 32) {
        short8 kf[2][2];
        for (int nt = 0; nt < 2; ++nt)
            for (int kk = 0; kk < 2; ++kk)
                kf[nt][kk] = frag16(Kp + (size_t)(n0 + nt * 16 + c) * 64 + kk * 32 + qd * 8);
        for (int mt = 0; mt < 2; ++mt) {
            f32x4 s0 = {0.f, 0.f, 0.f, 0.f}, s1 = {0.f, 0.f, 0.f, 0.f};
            s0 = MFMA16(qf[mt][0], kf[0][0], s0);
            s0 = MFMA16(qf[mt][1], kf[0][1], s0);
            s1 = MFMA16(qf[mt][0], kf[1][0], s1);
            s1 = MFMA16(qf[mt][1], kf[1][1], s1);
            for (int t = 0; t < 4; ++t)
                lpart[mt][t] += __expf(s0[t] * 0.125f) + __expf(s1[t] * 0.125f);
        }
    }
    float rcpl[2][4];
    for (int mt = 0; mt < 2; ++mt)
        for (int t = 0; t < 4; ++t) {
            float v = lpart[mt][t];
            v += __shfl_xor(v, 1); v += __shfl_xor(v, 2);
            v += __shfl_xor(v, 4); v += __shfl_xor(v, 8);
            rcpl[mt][t] = 1.0f / v;
        }

    // ---- pass B ----
    f32x4 oacc[2][4] = {};
    bf16* Pw = &Pbuf[wave][0];
    for (int n0 = 0; n0 < 2048; n0 += 32) {
        short8 kf[2][2];
        for (int nt = 0; nt < 2; ++nt)
            for (int kk = 0; kk < 2; ++kk)
                kf[nt][kk] = frag16(Kp + (size_t)(n0 + nt * 16 + c) * 64 + kk * 32 + qd * 8);
        for (int mt = 0; mt < 2; ++mt) {
            f32x4 s0 = {0.f, 0.f, 0.f, 0.f}, s1 = {0.f, 0.f, 0.f, 0.f};
            s0 = MFMA16(qf[mt][0], kf[0][0], s0);
            s0 = MFMA16(qf[mt][1], kf[0][1], s0);
            s1 = MFMA16(qf[mt][0], kf[1][0], s1);
            s1 = MFMA16(qf[mt][1], kf[1][1], s1);
            float* Arow = Ap + (size_t)(q0 + mt * 16 + qd * 4) * 2048 + n0;
            for (int t = 0; t < 4; ++t) {
                float p0 = __expf(s0[t] * 0.125f) * rcpl[mt][t];
                float p1 = __expf(s1[t] * 0.125f) * rcpl[mt][t];
                Arow[(size_t)t * 2048 + c] = p0;
                Arow[(size_t)t * 2048 + 16 + c] = p1;
                Pw[(mt * 16 + qd * 4 + t) * 40 + c] = __float2bfloat16(p0);
                Pw[(mt * 16 + qd * 4 + t) * 40 + 16 + c] = __float2bfloat16(p1);
            }
        }
        // P chunk is per-wave private: lgkmcnt(0) is enough (no __syncthreads)
        __builtin_amdgcn_sched_barrier(0);
        __builtin_amdgcn_s_waitcnt(0xC07F);   // lgkmcnt(0)
        __builtin_amdgcn_sched_barrier(0);
        for (int mt = 0; mt < 2; ++mt) {
            short8 pf = frag16(Pw + (mt * 16 + c) * 40 + qd * 8);
            for (int dt = 0; dt < 4; ++dt) {
                short8 vf = frag16(Vp + (size_t)(dt * 16 + c) * 2048 + n0 + qd * 8);
                oacc[mt][dt] = MFMA16(pf, vf, oacc[mt][dt]);
            }
        }
        __builtin_amdgcn_sched_barrier(0);
        __builtin_amdgcn_s_waitcnt(0xC07F);   // drain reads before next iter overwrites
        __builtin_amdgcn_sched_barrier(0);
    }
    // ctx[b, s, h*64+dh] bf16
    for (int mt = 0; mt < 2; ++mt)
        for (int dt = 0; dt < 4; ++dt)
            for (int t = 0; t < 4; ++t) {
                int s = q0 + mt * 16 + qd * 4 + t;
                ctx[(size_t)(b * 2048 + s) * 1024 + h * 64 + dt * 16 + c] =
                    __float2bfloat16(oacc[mt][dt][t]);
            }
}

// LayerNorm over rows of 1024 (gamma=1, beta=0, eps=1e-5, biased var)
__global__ __launch_bounds__(256) void ln_kernel(const float* __restrict__ Y, float* __restrict__ out) {
    const int row = blockIdx.x;
    const int lane = threadIdx.x & 63, wave = threadIdx.x >> 6;
    const float* yr = Y + (size_t)row * 1024;
    float4 v = *(const float4*)(yr + threadIdx.x * 4);
    float sum = v.x + v.y + v.z + v.w;
    float sq = v.x * v.x + v.y * v.y + v.z * v.z + v.w * v.w;
    for (int off = 1; off < 64; off <<= 1) {
        sum += __shfl_xor(sum, off);
        sq += __shfl_xor(sq, off);
    }
    __shared__ float s1[4], s2[4];
    if (lane == 0) { s1[wave] = sum; s2[wave] = sq; }
    __syncthreads();
    sum = s1[0] + s1[1] + s1[2] + s1[3];
    sq = s2[0] + s2[1] + s2[2] + s2[3];
    float mu = sum * (1.0f / 1024.0f);
    float var = sq * (1.0f / 1024.0f) - mu * mu;
    float inv = rsqrtf(var + 1e-5f);
    float4 o;
    o.x = (v.x - mu) * inv; o.y = (v.y - mu) * inv;
    o.z = (v.z - mu) * inv; o.w = (v.w - mu) * inv;
    *(float4*)(out + (size_t)row * 1024 + threadIdx.x * 4) = o;
}

extern "C" void kernel_launch(void* const* d_in, const int* in_sizes, int n_in,
                              void* d_out, int out_size, void* d_ws, size_t ws_size,
                              hipStream_t stream) {
    const float* in_q = (const float*)d_in[0];
    const float* in_k = (const float*)d_in[1];
    const float* in_v = (const float*)d_in[2];
    const float* w_q = (const float*)d_in[3];
    const float* w_k = (const float*)d_in[4];
    const float* w_v = (const float*)d_in[5];
    const float* w_fc = (const float*)d_in[6];

    char* ws = (char*)d_ws;
    const size_t MB = 1048576;
    bf16* Xq  = (bf16*)(ws);                    // 16 MB, reused as ctx after proj
    bf16* Xk  = (bf16*)(ws + 16 * MB);          // 16 MB, reused (with Xv) as Y after attn
    bf16* Xv  = (bf16*)(ws + 32 * MB);          // 16 MB
    bf16* Wqb = (bf16*)(ws + 48 * MB);          // 2 MB
    bf16* Wkb = (bf16*)(ws + 50 * MB);
    bf16* Wvb = (bf16*)(ws + 52 * MB);
    bf16* Wfcb = (bf16*)(ws + 54 * MB);
    bf16* Qb  = (bf16*)(ws + 56 * MB);          // 16 MB [b,h,s,dh]
    bf16* Kb  = (bf16*)(ws + 72 * MB);          // 16 MB
    bf16* Vb  = (bf16*)(ws + 88 * MB);          // 16 MB
    bf16* Vtb = (bf16*)(ws + 104 * MB);         // 16 MB [b,h,dh,s]  (peak ws = 120 MB)
    bf16* ctx = (bf16*)(ws);                    // 16 MB bf16 [b,s,h*dh]
    float* Y  = (float*)(ws + 16 * MB);         // 32 MB fp32

    float* out = (float*)d_out;                 // 8,388,608 floats
    float* attn = out + 8388608;                // 268,435,456 floats

    cvt_inputs<<<dim3(8192, 1, 3), 256, 0, stream>>>(in_q, in_k, in_v, Xq, Xk, Xv);
    cvt_weights<<<dim3(1024, 1, 4), 256, 0, stream>>>(w_q, w_k, w_v, w_fc, Wqb, Wkb, Wvb, Wfcb);
    proj_gemm<<<dim3(64, 8, 3), 256, 0, stream>>>(Xq, Xk, Xv, Wqb, Wkb, Wvb, Qb, Kb, Vb);
    transpose_v<<<dim3(32, 64), 256, 0, stream>>>(Vb, Vtb);
    attn_kernel<<<dim3(16, 64), 256, 0, stream>>>(Qb, Kb, Vtb, attn, ctx);
    fc_gemm<<<dim3(64, 8), 256, 0, stream>>>(ctx, Wfcb, in_q, Y);
    ln_kernel<<<8192, 256, 0, stream>>>(Y, out);
}